// Round 1
// baseline (198.924 us; speedup 1.0000x reference)
//
#include <hip/hip_runtime.h>
#include <math.h>

// DynamicRelationModeler: x=concat(img,txt) [512x512]; per r: a=x@Wl_r^T, b=x@Wr_r^T;
// h=a_i+b_j+b1_r; LN over H; s=relu(hn)@w2_r+b2_r; argmax/max over r; mask.
//
// ws layout (floats):
//   Aarr [4][512][512]  a_r[i][h]
//   Barr [4][512][512]  b'_r[j][h] (b1 folded in)
//   dotp [2][4][512][512]  k-split partial pairwise dots a_i . b'_j
//   Spart[2][4][512][512]  k-split partial relu-dot scores
//   ma/qa/mb/qb [4][512]   row mean (a), row sum-of-squares, same for b'
//   G    [4][512]          gamma per (r,k)
//   BW   [4][512][2]       packed (beta, w2) per (r,k)

namespace {
constexpr size_t PLANE  = 512 * 512;            // 262144
constexpr size_t OFF_A   = 0;
constexpr size_t OFF_B   = OFF_A + 4 * PLANE;   // 1048576
constexpr size_t OFF_DOT = OFF_B + 4 * PLANE;   // 2097152
constexpr size_t OFF_S   = OFF_DOT + 8 * PLANE; // 4194304
constexpr size_t OFF_MA  = OFF_S + 8 * PLANE;   // 6291456
constexpr size_t OFF_QA  = OFF_MA + 2048;
constexpr size_t OFF_MB  = OFF_QA + 2048;
constexpr size_t OFF_QB  = OFF_MB + 2048;
constexpr size_t OFF_G   = OFF_QB + 2048;       // gamma [2048]
constexpr size_t OFF_BW  = OFF_G + 2048;        // (beta,w2) [2048][2]
}

// ---------------- K0: input GEMM  C[n][4096] = x @ [Wl|Wr]^T ----------------
// grid 512 = 8 i-tiles x 64 col-tiles; block 256 (16x16 threads, 4x4 reg tile)
__global__ __launch_bounds__(256) void k0_gemm(const float* __restrict__ img,
                                               const float* __restrict__ txt,
                                               const float* __restrict__ W1,
                                               const float* __restrict__ b1,
                                               float* __restrict__ ws) {
  const int b = blockIdx.x;
  const int it = b >> 6;
  const int ct = b & 63;
  const int which = ct >> 5;      // 0 -> a (Wl), 1 -> b (Wr)
  const int r = (ct >> 3) & 3;
  const int ht = ct & 7;
  const int i0 = it << 6, h0 = ht << 6;
  const int t = threadIdx.x;
  const int tx = t & 15, ty = t >> 4;

  __shared__ float Xs[16 * 68];   // [k][i], pitch 68 -> 16B-aligned rows for b128 reads
  __shared__ float Wsm[16 * 68];  // [k][h]

  float acc[16], pacc[16];
#pragma unroll
  for (int p = 0; p < 16; ++p) { acc[p] = 0.f; pacc[p] = 0.f; }

  const int srow = t >> 2;
  const int sf4 = (t & 3) << 2;
  const int xi = i0 + srow;
  const float* xrow = (xi < 256) ? (img + (size_t)xi * 512)
                                 : (txt + (size_t)(xi - 256) * 512);
  const float* wrow = W1 + (size_t)(r * 512 + h0 + srow) * 1024 + which * 512;

  for (int k0 = 0; k0 < 512; k0 += 16) {
    const float4 xv = *(const float4*)(xrow + k0 + sf4);
    const float4 wv = *(const float4*)(wrow + k0 + sf4);
    __syncthreads();
    Xs[(sf4 + 0) * 68 + srow] = xv.x;
    Xs[(sf4 + 1) * 68 + srow] = xv.y;
    Xs[(sf4 + 2) * 68 + srow] = xv.z;
    Xs[(sf4 + 3) * 68 + srow] = xv.w;
    Wsm[(sf4 + 0) * 68 + srow] = wv.x;
    Wsm[(sf4 + 1) * 68 + srow] = wv.y;
    Wsm[(sf4 + 2) * 68 + srow] = wv.z;
    Wsm[(sf4 + 3) * 68 + srow] = wv.w;
    __syncthreads();
#pragma unroll
    for (int k = 0; k < 16; ++k) {
      const float4 a4 = *(const float4*)&Xs[k * 68 + 4 * ty];
      const float4 b4 = *(const float4*)&Wsm[k * 68 + 4 * tx];
      const float av[4] = {a4.x, a4.y, a4.z, a4.w};
      const float bv[4] = {b4.x, b4.y, b4.z, b4.w};
#pragma unroll
      for (int c = 0; c < 4; ++c)
#pragma unroll
        for (int d = 0; d < 4; ++d)
          pacc[c * 4 + d] = fmaf(av[c], bv[d], pacc[c * 4 + d]);
    }
    // fold per-stage partial into master (split accumulation: ~1e-7 error)
#pragma unroll
    for (int p = 0; p < 16; ++p) { acc[p] += pacc[p]; pacc[p] = 0.f; }
  }

  float4 bb = make_float4(0.f, 0.f, 0.f, 0.f);
  if (which) bb = *(const float4*)(b1 + r * 512 + h0 + 4 * tx);
  float* dst = ws + (which ? OFF_B : OFF_A) + (size_t)r * PLANE;
#pragma unroll
  for (int c = 0; c < 4; ++c) {
    float4 v;
    v.x = acc[c * 4 + 0] + bb.x;
    v.y = acc[c * 4 + 1] + bb.y;
    v.z = acc[c * 4 + 2] + bb.z;
    v.w = acc[c * 4 + 3] + bb.w;
    *(float4*)(dst + (size_t)(i0 + 4 * ty + c) * 512 + h0 + 4 * tx) = v;
  }
}

// ---------------- K1: row stats + gamma / (beta,w2) packing ----------------
// one wave per (which, r, row); grid 1024 x 256
__global__ __launch_bounds__(256) void k1_stats(float* __restrict__ ws,
                                                const float* __restrict__ gamma,
                                                const float* __restrict__ beta,
                                                const float* __restrict__ w2) {
  const int t = threadIdx.x;
  const int gw = (blockIdx.x * 256 + t) >> 6;  // 0..4095
  const int lane = t & 63;
  const int which = gw >> 11;
  const int rr = (gw >> 9) & 3;
  const int row = gw & 511;
  const float* src =
      ws + (which ? OFF_B : OFF_A) + (size_t)(rr * 512 + row) * 512 + lane * 8;
  float s = 0.f, q = 0.f;
#pragma unroll
  for (int c = 0; c < 2; ++c) {
    const float4 v = *(const float4*)(src + c * 4);
    s += v.x + v.y + v.z + v.w;
    q += v.x * v.x + v.y * v.y + v.z * v.z + v.w * v.w;
  }
#pragma unroll
  for (int off = 32; off >= 1; off >>= 1) {
    s += __shfl_down(s, off, 64);
    q += __shfl_down(q, off, 64);
  }
  if (lane == 0) {
    ws[(which ? OFF_MB : OFF_MA) + rr * 512 + row] = s * (1.f / 512.f);
    ws[(which ? OFF_QB : OFF_QA) + rr * 512 + row] = q;
  }
  if (blockIdx.x < 8) {
    const int idx = blockIdx.x * 256 + t;  // 0..2047 == r*512+k
    ws[OFF_G + idx] = gamma[idx];
    float2 bw;
    bw.x = beta[idx];
    bw.y = w2[idx];
    *(float2*)(ws + OFF_BW + (size_t)idx * 2) = bw;
  }
}

// ---------------- K2: pairwise dot  dotp[ks][r][i][j] = sum_k a.b' ----------------
// grid 512 = 8jt x 8it x 4r x 2ks; block 256 (16x16, 4x4 reg tile)
__global__ __launch_bounds__(256) void k2_dot(float* __restrict__ ws) {
  const int b = blockIdx.x;
  const int jt = b & 7, it = (b >> 3) & 7, r = (b >> 6) & 3, ks = b >> 8;
  const int i0 = it << 6, j0 = jt << 6;
  const int kb = ks << 8;
  const int t = threadIdx.x;
  const int tx = t & 15, ty = t >> 4;

  __shared__ float As[16 * 68];
  __shared__ float Bs[16 * 68];

  float acc[16];
#pragma unroll
  for (int p = 0; p < 16; ++p) acc[p] = 0.f;

  const int srow = t >> 2, sf4 = (t & 3) << 2;
  const float* arow = ws + OFF_A + (size_t)(r * 512 + i0 + srow) * 512 + kb;
  const float* brow = ws + OFF_B + (size_t)(r * 512 + j0 + srow) * 512 + kb;

  for (int k0 = 0; k0 < 256; k0 += 16) {
    const float4 av = *(const float4*)(arow + k0 + sf4);
    const float4 bv = *(const float4*)(brow + k0 + sf4);
    __syncthreads();
    As[(sf4 + 0) * 68 + srow] = av.x;
    As[(sf4 + 1) * 68 + srow] = av.y;
    As[(sf4 + 2) * 68 + srow] = av.z;
    As[(sf4 + 3) * 68 + srow] = av.w;
    Bs[(sf4 + 0) * 68 + srow] = bv.x;
    Bs[(sf4 + 1) * 68 + srow] = bv.y;
    Bs[(sf4 + 2) * 68 + srow] = bv.z;
    Bs[(sf4 + 3) * 68 + srow] = bv.w;
    __syncthreads();
#pragma unroll
    for (int k = 0; k < 16; ++k) {
      const float4 a4 = *(const float4*)&As[k * 68 + 4 * ty];
      const float4 b4 = *(const float4*)&Bs[k * 68 + 4 * tx];
      const float av2[4] = {a4.x, a4.y, a4.z, a4.w};
      const float bv2[4] = {b4.x, b4.y, b4.z, b4.w};
#pragma unroll
      for (int c = 0; c < 4; ++c)
#pragma unroll
        for (int d = 0; d < 4; ++d)
          acc[c * 4 + d] = fmaf(av2[c], bv2[d], acc[c * 4 + d]);
    }
  }
  float* dst = ws + OFF_DOT + (size_t)ks * (4 * PLANE) + (size_t)r * PLANE;
#pragma unroll
  for (int c = 0; c < 4; ++c) {
    float4 v;
    v.x = acc[c * 4 + 0]; v.y = acc[c * 4 + 1];
    v.z = acc[c * 4 + 2]; v.w = acc[c * 4 + 3];
    *(float4*)(dst + (size_t)(i0 + 4 * ty + c) * 512 + j0 + 4 * tx) = v;
  }
}

// ---------------- K3: score kernel (centered LN, 4-op inner loop) ----------------
// grid 512 = 8jt x 8it x 4r x 2ks; block 512 (32tx x 16ty; 4i x 2j reg tile)
// mean is separable: mu_ij = ma_i + mb_j, so stage centered+gamma-scaled rows:
//   At = (a - ma)*gamma_k, Bt = (b - mb)*gamma_k  ->  hn = (At+Bt)*Sv + beta_k
// LDS holds the chunk TRANSPOSED [k][row] so inner reads are b128/b64 broadcasts.
__global__ __launch_bounds__(512) void k3_score(float* __restrict__ ws) {
  const int b = blockIdx.x;
  const int jt = b & 7, it = (b >> 3) & 7, r = (b >> 6) & 3, ks = b >> 8;
  const int i0 = it << 6, j0 = jt << 6;
  const int t = threadIdx.x;
  const int tx = t & 31, ty = t >> 5;

  __shared__ float As2[64 * 68];  // [k][i], pitch 68 (16B-aligned rows)
  __shared__ float Bs2[64 * 68];  // [k][j]
  __shared__ float bwS[64 * 2];   // (beta, w2) per k of current chunk

  // per-pair LN inverse-sigma: Sv = 1/sqrt(var+eps); shift handled by centering
  const float4 mav = *(const float4*)(ws + OFF_MA + r * 512 + i0 + 4 * ty);
  const float4 qav = *(const float4*)(ws + OFF_QA + r * 512 + i0 + 4 * ty);
  const float2 mbv = *(const float2*)(ws + OFF_MB + r * 512 + j0 + 2 * tx);
  const float2 qbv = *(const float2*)(ws + OFF_QB + r * 512 + j0 + 2 * tx);
  const float mavA[4] = {mav.x, mav.y, mav.z, mav.w};
  const float qavA[4] = {qav.x, qav.y, qav.z, qav.w};
  const float mbA[2] = {mbv.x, mbv.y};
  const float qbA[2] = {qbv.x, qbv.y};
  float Sv[8], acc[8];
#pragma unroll
  for (int c = 0; c < 4; ++c) {
    const size_t doff = (size_t)r * PLANE + (size_t)(i0 + 4 * ty + c) * 512 + j0 + 2 * tx;
    const float2 d0 = *(const float2*)(ws + OFF_DOT + doff);
    const float2 d1 = *(const float2*)(ws + OFF_DOT + 4 * PLANE + doff);
    const float dA[2] = {d0.x + d1.x, d0.y + d1.y};
#pragma unroll
    for (int d = 0; d < 2; ++d) {
      const int p = c * 2 + d;
      const float mu = mavA[c] + mbA[d];
      const float msq = (qavA[c] + qbA[d] + 2.f * dA[d]) * (1.f / 512.f);
      const float var = msq - mu * mu;
      Sv[p] = 1.0f / sqrtf(var + 1e-5f);   // precise (no fast-math)
      acc[p] = 0.f;
    }
  }

  const int kbase = ks << 8;
  const int srow = t >> 4, sf4 = (t & 15) << 2;  // srow 0..31, sf4 0..60
  const int ra = i0 + srow, rb = j0 + srow;
  // row means for centering (hot in L2; 4 scalar broadcasts per wave)
  const float maA2[2] = {ws[OFF_MA + r * 512 + ra], ws[OFF_MA + r * 512 + ra + 32]};
  const float mbA2[2] = {ws[OFF_MB + r * 512 + rb], ws[OFF_MB + r * 512 + rb + 32]};

  for (int kc = 0; kc < 4; ++kc) {
    const int kb = kbase + (kc << 6);
    const float4 gv = *(const float4*)(ws + OFF_G + r * 512 + kb + sf4);
    float4 avs[2], bvs[2];
#pragma unroll
    for (int c2 = 0; c2 < 2; ++c2) {
      avs[c2] = *(const float4*)(ws + OFF_A + (size_t)(r * 512 + ra + 32 * c2) * 512 + kb + sf4);
      bvs[c2] = *(const float4*)(ws + OFF_B + (size_t)(r * 512 + rb + 32 * c2) * 512 + kb + sf4);
    }
    float2 bwv = make_float2(0.f, 0.f);
    if (t < 64) bwv = *(const float2*)(ws + OFF_BW + (size_t)(r * 512 + kb + t) * 2);
    __syncthreads();  // protect previous chunk's LDS reads
    {
      const float ga[4] = {gv.x, gv.y, gv.z, gv.w};
#pragma unroll
      for (int c2 = 0; c2 < 2; ++c2) {
        const int row = srow + 32 * c2;
        const float aq[4] = {avs[c2].x, avs[c2].y, avs[c2].z, avs[c2].w};
        const float bq[4] = {bvs[c2].x, bvs[c2].y, bvs[c2].z, bvs[c2].w};
#pragma unroll
        for (int q = 0; q < 4; ++q) {
          As2[(sf4 + q) * 68 + row] = (aq[q] - maA2[c2]) * ga[q];
          Bs2[(sf4 + q) * 68 + row] = (bq[q] - mbA2[c2]) * ga[q];
        }
      }
    }
    if (t < 64) *(float2*)(bwS + 2 * t) = bwv;
    __syncthreads();

    float cacc[8];
#pragma unroll
    for (int p = 0; p < 8; ++p) cacc[p] = 0.f;

#pragma unroll 8
    for (int k = 0; k < 64; ++k) {
      const float4 aA = *(const float4*)&As2[k * 68 + 4 * ty];  // b128, 2-addr broadcast
      const float2 bB = *(const float2*)&Bs2[k * 68 + 2 * tx];  // b64, 2-way (free)
      const float2 bw = *(const float2*)&bwS[2 * k];            // b64 broadcast
      const float aq[4] = {aA.x, aA.y, aA.z, aA.w};
      const float bq[2] = {bB.x, bB.y};
#pragma unroll
      for (int c = 0; c < 4; ++c)
#pragma unroll
        for (int d = 0; d < 2; ++d) {
          const int p = c * 2 + d;
          const float u = aq[c] + bq[d];              // (a-ma)g + (b-mb)g
          const float hn = fmaf(u, Sv[p], bw.x);      // *Sv + beta
          const float m = fmaxf(hn, 0.f);             // relu
          cacc[p] = fmaf(m, bw.y, cacc[p]);           // *w2, accumulate
        }
    }
    // chunked accumulation: keeps summation error ~2e-7
#pragma unroll
    for (int p = 0; p < 8; ++p) acc[p] += cacc[p];
  }

  float* dst = ws + OFF_S + (size_t)ks * (4 * PLANE) + (size_t)r * PLANE;
#pragma unroll
  for (int c = 0; c < 4; ++c) {
    float2 v;
    v.x = acc[c * 2 + 0];
    v.y = acc[c * 2 + 1];
    *(float2*)(dst + (size_t)(i0 + 4 * ty + c) * 512 + j0 + 2 * tx) = v;
  }
}

// ---------------- K4: combine + outputs ----------------
__global__ __launch_bounds__(256) void k4_combine(const float* __restrict__ ws,
                                                  const float* __restrict__ img,
                                                  const float* __restrict__ txt,
                                                  const float* __restrict__ b2,
                                                  float* __restrict__ out) {
  const int idx = blockIdx.x * 256 + threadIdx.x;  // 0..262143
  const int i = idx >> 9, j = idx & 511;
  const float* s0 = ws + OFF_S;
  const float* s1 = ws + OFF_S + 4 * PLANE;
  float best = -3.4e38f;
  int rel = 0;
#pragma unroll
  for (int r = 0; r < 4; ++r) {
    const float s = s0[r * PLANE + idx] + s1[r * PLANE + idx] + b2[r];
    if (s > best) { best = s; rel = r; }  // strict > == first-index argmax
  }
  out[idx] = (i < 256) ? img[idx] : txt[idx - 131072];
  out[PLANE + idx] = best;
  out[2 * PLANE + idx] = (float)rel;
  // match numpy: float32 best promoted to double vs python-float 0.2
  out[3 * PLANE + idx] = (i != j && (double)best > 0.2) ? 1.0f : 0.0f;
}

extern "C" void kernel_launch(void* const* d_in, const int* in_sizes, int n_in,
                              void* d_out, int out_size, void* d_ws, size_t ws_size,
                              hipStream_t stream) {
  const float* img   = (const float*)d_in[0];
  const float* txt   = (const float*)d_in[1];
  const float* W1    = (const float*)d_in[2];
  const float* b1    = (const float*)d_in[3];
  const float* gamma = (const float*)d_in[4];
  const float* beta  = (const float*)d_in[5];
  const float* w2    = (const float*)d_in[6];
  const float* b2    = (const float*)d_in[7];
  float* ws  = (float*)d_ws;
  float* out = (float*)d_out;
  (void)in_sizes; (void)n_in; (void)out_size; (void)ws_size;

  hipLaunchKernelGGL(k0_gemm,    dim3(512),  dim3(256), 0, stream, img, txt, W1, b1, ws);
  hipLaunchKernelGGL(k1_stats,   dim3(1024), dim3(256), 0, stream, ws, gamma, beta, w2);
  hipLaunchKernelGGL(k2_dot,     dim3(512),  dim3(256), 0, stream, ws);
  hipLaunchKernelGGL(k3_score,   dim3(512),  dim3(512), 0, stream, ws);
  hipLaunchKernelGGL(k4_combine, dim3(1024), dim3(256), 0, stream, ws, img, txt, b2, out);
}

// Round 2
// 194.556 us; speedup vs baseline: 1.0224x; 1.0224x over previous
//
#include <hip/hip_runtime.h>
#include <math.h>

// DynamicRelationModeler: x=concat(img,txt) [512x512]; per r: a=x@Wl_r^T, b=x@Wr_r^T;
// h=a_i+b_j+b1_r; LN over H; s=relu(hn)@w2_r+b2_r; argmax/max over r; mask.
//
// ws layout (floats):
//   Aarr [4][512][512]  a_r[i][h]
//   Barr [4][512][512]  b'_r[j][h] (b1 folded in)
//   dotp [2][4][512][512]  k-split partial pairwise dots a_i . b'_j
//   Spart[2][4][512][512]  k-split partial relu-dot scores
//   ma/qa/mb/qb [4][512]   row mean (a), row sum-of-squares, same for b'
//   G    [4][512]          gamma per (r,k)
//   BW   [4][512][2]       packed (beta, w2) per (r,k)

namespace {
constexpr size_t PLANE  = 512 * 512;            // 262144
constexpr size_t OFF_A   = 0;
constexpr size_t OFF_B   = OFF_A + 4 * PLANE;   // 1048576
constexpr size_t OFF_DOT = OFF_B + 4 * PLANE;   // 2097152
constexpr size_t OFF_S   = OFF_DOT + 8 * PLANE; // 4194304
constexpr size_t OFF_MA  = OFF_S + 8 * PLANE;   // 6291456
constexpr size_t OFF_QA  = OFF_MA + 2048;
constexpr size_t OFF_MB  = OFF_QA + 2048;
constexpr size_t OFF_QB  = OFF_MB + 2048;
constexpr size_t OFF_G   = OFF_QB + 2048;       // gamma [2048]
constexpr size_t OFF_BW  = OFF_G + 2048;        // (beta,w2) [2048][2]
}

// ---------------- K0: input GEMM  C[n][4096] = x @ [Wl|Wr]^T ----------------
// grid 512 = 8 i-tiles x 64 col-tiles; block 256 (16x16 threads, 4x4 reg tile)
__global__ __launch_bounds__(256) void k0_gemm(const float* __restrict__ img,
                                               const float* __restrict__ txt,
                                               const float* __restrict__ W1,
                                               const float* __restrict__ b1,
                                               float* __restrict__ ws) {
  const int b = blockIdx.x;
  const int it = b >> 6;
  const int ct = b & 63;
  const int which = ct >> 5;      // 0 -> a (Wl), 1 -> b (Wr)
  const int r = (ct >> 3) & 3;
  const int ht = ct & 7;
  const int i0 = it << 6, h0 = ht << 6;
  const int t = threadIdx.x;
  const int tx = t & 15, ty = t >> 4;

  __shared__ float Xs[16 * 68];   // [k][i], pitch 68 -> 16B-aligned rows for b128 reads
  __shared__ float Wsm[16 * 68];  // [k][h]

  float acc[16], pacc[16];
#pragma unroll
  for (int p = 0; p < 16; ++p) { acc[p] = 0.f; pacc[p] = 0.f; }

  const int srow = t >> 2;
  const int sf4 = (t & 3) << 2;
  const int xi = i0 + srow;
  const float* xrow = (xi < 256) ? (img + (size_t)xi * 512)
                                 : (txt + (size_t)(xi - 256) * 512);
  const float* wrow = W1 + (size_t)(r * 512 + h0 + srow) * 1024 + which * 512;

  for (int k0 = 0; k0 < 512; k0 += 16) {
    const float4 xv = *(const float4*)(xrow + k0 + sf4);
    const float4 wv = *(const float4*)(wrow + k0 + sf4);
    __syncthreads();
    Xs[(sf4 + 0) * 68 + srow] = xv.x;
    Xs[(sf4 + 1) * 68 + srow] = xv.y;
    Xs[(sf4 + 2) * 68 + srow] = xv.z;
    Xs[(sf4 + 3) * 68 + srow] = xv.w;
    Wsm[(sf4 + 0) * 68 + srow] = wv.x;
    Wsm[(sf4 + 1) * 68 + srow] = wv.y;
    Wsm[(sf4 + 2) * 68 + srow] = wv.z;
    Wsm[(sf4 + 3) * 68 + srow] = wv.w;
    __syncthreads();
#pragma unroll
    for (int k = 0; k < 16; ++k) {
      const float4 a4 = *(const float4*)&Xs[k * 68 + 4 * ty];
      const float4 b4 = *(const float4*)&Wsm[k * 68 + 4 * tx];
      const float av[4] = {a4.x, a4.y, a4.z, a4.w};
      const float bv[4] = {b4.x, b4.y, b4.z, b4.w};
#pragma unroll
      for (int c = 0; c < 4; ++c)
#pragma unroll
        for (int d = 0; d < 4; ++d)
          pacc[c * 4 + d] = fmaf(av[c], bv[d], pacc[c * 4 + d]);
    }
    // fold per-stage partial into master (split accumulation: ~1e-7 error)
#pragma unroll
    for (int p = 0; p < 16; ++p) { acc[p] += pacc[p]; pacc[p] = 0.f; }
  }

  float4 bb = make_float4(0.f, 0.f, 0.f, 0.f);
  if (which) bb = *(const float4*)(b1 + r * 512 + h0 + 4 * tx);
  float* dst = ws + (which ? OFF_B : OFF_A) + (size_t)r * PLANE;
#pragma unroll
  for (int c = 0; c < 4; ++c) {
    float4 v;
    v.x = acc[c * 4 + 0] + bb.x;
    v.y = acc[c * 4 + 1] + bb.y;
    v.z = acc[c * 4 + 2] + bb.z;
    v.w = acc[c * 4 + 3] + bb.w;
    *(float4*)(dst + (size_t)(i0 + 4 * ty + c) * 512 + h0 + 4 * tx) = v;
  }
}

// ---------------- K1: row stats + gamma / (beta,w2) packing ----------------
// one wave per (which, r, row); grid 1024 x 256
__global__ __launch_bounds__(256) void k1_stats(float* __restrict__ ws,
                                                const float* __restrict__ gamma,
                                                const float* __restrict__ beta,
                                                const float* __restrict__ w2) {
  const int t = threadIdx.x;
  const int gw = (blockIdx.x * 256 + t) >> 6;  // 0..4095
  const int lane = t & 63;
  const int which = gw >> 11;
  const int rr = (gw >> 9) & 3;
  const int row = gw & 511;
  const float* src =
      ws + (which ? OFF_B : OFF_A) + (size_t)(rr * 512 + row) * 512 + lane * 8;
  float s = 0.f, q = 0.f;
#pragma unroll
  for (int c = 0; c < 2; ++c) {
    const float4 v = *(const float4*)(src + c * 4);
    s += v.x + v.y + v.z + v.w;
    q += v.x * v.x + v.y * v.y + v.z * v.z + v.w * v.w;
  }
#pragma unroll
  for (int off = 32; off >= 1; off >>= 1) {
    s += __shfl_down(s, off, 64);
    q += __shfl_down(q, off, 64);
  }
  if (lane == 0) {
    ws[(which ? OFF_MB : OFF_MA) + rr * 512 + row] = s * (1.f / 512.f);
    ws[(which ? OFF_QB : OFF_QA) + rr * 512 + row] = q;
  }
  if (blockIdx.x < 8) {
    const int idx = blockIdx.x * 256 + t;  // 0..2047 == r*512+k
    ws[OFF_G + idx] = gamma[idx];
    float2 bw;
    bw.x = beta[idx];
    bw.y = w2[idx];
    *(float2*)(ws + OFF_BW + (size_t)idx * 2) = bw;
  }
}

// ---------------- K2: pairwise dot  dotp[ks][r][i][j] = sum_k a.b' ----------------
// grid 512 = 8jt x 8it x 4r x 2ks; block 256 (16x16, 4x4 reg tile)
__global__ __launch_bounds__(256) void k2_dot(float* __restrict__ ws) {
  const int b = blockIdx.x;
  const int jt = b & 7, it = (b >> 3) & 7, r = (b >> 6) & 3, ks = b >> 8;
  const int i0 = it << 6, j0 = jt << 6;
  const int kb = ks << 8;
  const int t = threadIdx.x;
  const int tx = t & 15, ty = t >> 4;

  __shared__ float As[16 * 68];
  __shared__ float Bs[16 * 68];

  float acc[16];
#pragma unroll
  for (int p = 0; p < 16; ++p) acc[p] = 0.f;

  const int srow = t >> 2, sf4 = (t & 3) << 2;
  const float* arow = ws + OFF_A + (size_t)(r * 512 + i0 + srow) * 512 + kb;
  const float* brow = ws + OFF_B + (size_t)(r * 512 + j0 + srow) * 512 + kb;

  for (int k0 = 0; k0 < 256; k0 += 16) {
    const float4 av = *(const float4*)(arow + k0 + sf4);
    const float4 bv = *(const float4*)(brow + k0 + sf4);
    __syncthreads();
    As[(sf4 + 0) * 68 + srow] = av.x;
    As[(sf4 + 1) * 68 + srow] = av.y;
    As[(sf4 + 2) * 68 + srow] = av.z;
    As[(sf4 + 3) * 68 + srow] = av.w;
    Bs[(sf4 + 0) * 68 + srow] = bv.x;
    Bs[(sf4 + 1) * 68 + srow] = bv.y;
    Bs[(sf4 + 2) * 68 + srow] = bv.z;
    Bs[(sf4 + 3) * 68 + srow] = bv.w;
    __syncthreads();
#pragma unroll
    for (int k = 0; k < 16; ++k) {
      const float4 a4 = *(const float4*)&As[k * 68 + 4 * ty];
      const float4 b4 = *(const float4*)&Bs[k * 68 + 4 * tx];
      const float av2[4] = {a4.x, a4.y, a4.z, a4.w};
      const float bv2[4] = {b4.x, b4.y, b4.z, b4.w};
#pragma unroll
      for (int c = 0; c < 4; ++c)
#pragma unroll
        for (int d = 0; d < 4; ++d)
          acc[c * 4 + d] = fmaf(av2[c], bv2[d], acc[c * 4 + d]);
    }
  }
  float* dst = ws + OFF_DOT + (size_t)ks * (4 * PLANE) + (size_t)r * PLANE;
#pragma unroll
  for (int c = 0; c < 4; ++c) {
    float4 v;
    v.x = acc[c * 4 + 0]; v.y = acc[c * 4 + 1];
    v.z = acc[c * 4 + 2]; v.w = acc[c * 4 + 3];
    *(float4*)(dst + (size_t)(i0 + 4 * ty + c) * 512 + j0 + 4 * tx) = v;
  }
}

// ---------------- K3: score kernel v3 ----------------
// grid 512 = 8jt x 8it x 4r x 2ks; block 256 (16tx x 16ty; 4i x 4j reg tile).
// Centered LN: stage At=(a-ma)*g, Bt=(b-mb)*g; hn=(At+Bt)*Sv+beta -> 4 ops/tuple,
// 64 VALU per 3 LDS reads per k (2x the ILP of v2, so 2 waves/SIMD self-hide).
// LDS [k][row] pitch 68 with XOR swizzle (row-block ^= (k>>2)&7 at 16B grain):
// stores 2-way (free, was 8-way), reads stay b128 conflict-free.
// Global loads for chunk kc+1 issued before compute of chunk kc (latency hidden).
__global__ __launch_bounds__(256) void k3_score(float* __restrict__ ws) {
  const int b = blockIdx.x;
  const int jt = b & 7, it = (b >> 3) & 7, r = (b >> 6) & 3, ks = b >> 8;
  const int i0 = it << 6, j0 = jt << 6;
  const int t = threadIdx.x;
  const int tx = t & 15, ty = t >> 4;

  __shared__ float As2[64 * 68];  // [k][row-swizzled], pitch 68 (16B-aligned rows)
  __shared__ float Bs2[64 * 68];
  __shared__ float bwS[64 * 2];   // (beta, w2) per k of current chunk

  // ---- per-pair LN inverse-sigma Sv[16]; shift handled by centering ----
  const float4 mav = *(const float4*)(ws + OFF_MA + r * 512 + i0 + 4 * ty);
  const float4 qav = *(const float4*)(ws + OFF_QA + r * 512 + i0 + 4 * ty);
  const float4 mbv = *(const float4*)(ws + OFF_MB + r * 512 + j0 + 4 * tx);
  const float4 qbv = *(const float4*)(ws + OFF_QB + r * 512 + j0 + 4 * tx);
  const float mavA[4] = {mav.x, mav.y, mav.z, mav.w};
  const float qavA[4] = {qav.x, qav.y, qav.z, qav.w};
  const float mbA[4] = {mbv.x, mbv.y, mbv.z, mbv.w};
  const float qbA[4] = {qbv.x, qbv.y, qbv.z, qbv.w};
  float Sv[16], acc[16];
#pragma unroll
  for (int c = 0; c < 4; ++c) {
    const size_t doff = (size_t)r * PLANE + (size_t)(i0 + 4 * ty + c) * 512 + j0 + 4 * tx;
    const float4 d0 = *(const float4*)(ws + OFF_DOT + doff);
    const float4 d1 = *(const float4*)(ws + OFF_DOT + 4 * PLANE + doff);
    const float dA[4] = {d0.x + d1.x, d0.y + d1.y, d0.z + d1.z, d0.w + d1.w};
#pragma unroll
    for (int d = 0; d < 4; ++d) {
      const int p = c * 4 + d;
      const float mu = mavA[c] + mbA[d];
      const float msq = (qavA[c] + qbA[d] + 2.f * dA[d]) * (1.f / 512.f);
      const float var = msq - mu * mu;
      Sv[p] = 1.0f / sqrtf(var + 1e-5f);   // precise (no fast-math)
      acc[p] = 0.f;
    }
  }

  // ---- staging geometry: thread loads 4 rows (srow+16*c2) x 4 k (sf4..+3) ----
  const int kbase = ks << 8;
  const int srow = ty;              // 0..15
  const int sf4 = tx << 2;          // 0..60; (k>>2)&7 == tx&7 for all 4 staged k
  const int sblk = tx & 7;
  // centering means for the staged rows (scalar, L2-hot)
  float maR[4], mbR[4];
#pragma unroll
  for (int c2 = 0; c2 < 4; ++c2) {
    maR[c2] = ws[OFF_MA + r * 512 + i0 + srow + 16 * c2];
    mbR[c2] = ws[OFF_MB + r * 512 + j0 + srow + 16 * c2];
  }

  float4 aC[4], bC[4], gC;
  float2 bwC = make_float2(0.f, 0.f);
  {
    const int kb = kbase;
    gC = *(const float4*)(ws + OFF_G + r * 512 + kb + sf4);
#pragma unroll
    for (int c2 = 0; c2 < 4; ++c2) {
      aC[c2] = *(const float4*)(ws + OFF_A + (size_t)(r * 512 + i0 + srow + 16 * c2) * 512 + kb + sf4);
      bC[c2] = *(const float4*)(ws + OFF_B + (size_t)(r * 512 + j0 + srow + 16 * c2) * 512 + kb + sf4);
    }
    if (t < 64) bwC = *(const float2*)(ws + OFF_BW + (size_t)(r * 512 + kb + t) * 2);
  }

#pragma unroll
  for (int kc = 0; kc < 4; ++kc) {
    __syncthreads();  // previous chunk's LDS reads complete before overwrite
    // ---- stage current chunk (centered + gamma-scaled), swizzled stores ----
    {
      const float ga[4] = {gC.x, gC.y, gC.z, gC.w};
#pragma unroll
      for (int c2 = 0; c2 < 4; ++c2) {
        const int row = srow + 16 * c2;
        const int off = (((row >> 2) ^ sblk) << 2) + (row & 3);
        const float aq[4] = {aC[c2].x, aC[c2].y, aC[c2].z, aC[c2].w};
        const float bq[4] = {bC[c2].x, bC[c2].y, bC[c2].z, bC[c2].w};
#pragma unroll
        for (int q = 0; q < 4; ++q) {
          As2[(sf4 + q) * 68 + off] = (aq[q] - maR[c2]) * ga[q];
          Bs2[(sf4 + q) * 68 + off] = (bq[q] - mbR[c2]) * ga[q];
        }
      }
      if (t < 64) *(float2*)(bwS + 2 * t) = bwC;
    }
    // ---- prefetch next chunk's globals (overlap with compute below) ----
    if (kc < 3) {
      const int kb = kbase + ((kc + 1) << 6);
      gC = *(const float4*)(ws + OFF_G + r * 512 + kb + sf4);
#pragma unroll
      for (int c2 = 0; c2 < 4; ++c2) {
        aC[c2] = *(const float4*)(ws + OFF_A + (size_t)(r * 512 + i0 + srow + 16 * c2) * 512 + kb + sf4);
        bC[c2] = *(const float4*)(ws + OFF_B + (size_t)(r * 512 + j0 + srow + 16 * c2) * 512 + kb + sf4);
      }
      if (t < 64) bwC = *(const float2*)(ws + OFF_BW + (size_t)(r * 512 + kb + t) * 2);
    }
    __syncthreads();  // staged data visible

    float cacc[16];
#pragma unroll
    for (int p = 0; p < 16; ++p) cacc[p] = 0.f;

#pragma unroll 4
    for (int k = 0; k < 64; ++k) {
      const int K = (k >> 2) & 7;
      const float4 aA = *(const float4*)&As2[k * 68 + ((ty ^ K) << 2)];  // b128, 4 uniq addrs
      const float4 bB = *(const float4*)&Bs2[k * 68 + ((tx ^ K) << 2)];  // b128, 2-way free
      const float2 bw = *(const float2*)&bwS[2 * k];                     // b64 broadcast
      const float aq[4] = {aA.x, aA.y, aA.z, aA.w};
      const float bq[4] = {bB.x, bB.y, bB.z, bB.w};
#pragma unroll
      for (int c = 0; c < 4; ++c)
#pragma unroll
        for (int d = 0; d < 4; ++d) {
          const int p = c * 4 + d;
          const float u = aq[c] + bq[d];              // (a-ma)g + (b-mb)g
          const float hn = fmaf(u, Sv[p], bw.x);      // *Sv + beta
          const float m = fmaxf(hn, 0.f);             // relu
          cacc[p] = fmaf(m, bw.y, cacc[p]);           // *w2, accumulate
        }
    }
    // chunked accumulation: keeps summation error ~2e-7
#pragma unroll
    for (int p = 0; p < 16; ++p) acc[p] += cacc[p];
  }

  float* dst = ws + OFF_S + (size_t)ks * (4 * PLANE) + (size_t)r * PLANE;
#pragma unroll
  for (int c = 0; c < 4; ++c) {
    float4 v;
    v.x = acc[c * 4 + 0];
    v.y = acc[c * 4 + 1];
    v.z = acc[c * 4 + 2];
    v.w = acc[c * 4 + 3];
    *(float4*)(dst + (size_t)(i0 + 4 * ty + c) * 512 + j0 + 4 * tx) = v;
  }
}

// ---------------- K4: combine + outputs ----------------
__global__ __launch_bounds__(256) void k4_combine(const float* __restrict__ ws,
                                                  const float* __restrict__ img,
                                                  const float* __restrict__ txt,
                                                  const float* __restrict__ b2,
                                                  float* __restrict__ out) {
  const int idx = blockIdx.x * 256 + threadIdx.x;  // 0..262143
  const int i = idx >> 9, j = idx & 511;
  const float* s0 = ws + OFF_S;
  const float* s1 = ws + OFF_S + 4 * PLANE;
  float best = -3.4e38f;
  int rel = 0;
#pragma unroll
  for (int r = 0; r < 4; ++r) {
    const float s = s0[r * PLANE + idx] + s1[r * PLANE + idx] + b2[r];
    if (s > best) { best = s; rel = r; }  // strict > == first-index argmax
  }
  out[idx] = (i < 256) ? img[idx] : txt[idx - 131072];
  out[PLANE + idx] = best;
  out[2 * PLANE + idx] = (float)rel;
  // match numpy: float32 best promoted to double vs python-float 0.2
  out[3 * PLANE + idx] = (i != j && (double)best > 0.2) ? 1.0f : 0.0f;
}

extern "C" void kernel_launch(void* const* d_in, const int* in_sizes, int n_in,
                              void* d_out, int out_size, void* d_ws, size_t ws_size,
                              hipStream_t stream) {
  const float* img   = (const float*)d_in[0];
  const float* txt   = (const float*)d_in[1];
  const float* W1    = (const float*)d_in[2];
  const float* b1    = (const float*)d_in[3];
  const float* gamma = (const float*)d_in[4];
  const float* beta  = (const float*)d_in[5];
  const float* w2    = (const float*)d_in[6];
  const float* b2    = (const float*)d_in[7];
  float* ws  = (float*)d_ws;
  float* out = (float*)d_out;
  (void)in_sizes; (void)n_in; (void)out_size; (void)ws_size;

  hipLaunchKernelGGL(k0_gemm,    dim3(512),  dim3(256), 0, stream, img, txt, W1, b1, ws);
  hipLaunchKernelGGL(k1_stats,   dim3(1024), dim3(256), 0, stream, ws, gamma, beta, w2);
  hipLaunchKernelGGL(k2_dot,     dim3(512),  dim3(256), 0, stream, ws);
  hipLaunchKernelGGL(k3_score,   dim3(512),  dim3(256), 0, stream, ws);
  hipLaunchKernelGGL(k4_combine, dim3(1024), dim3(256), 0, stream, ws, img, txt, b2, out);
}